// Round 8
// baseline (456.610 us; speedup 1.0000x reference)
//
#include <hip/hip_runtime.h>

typedef _Float16 f16x8 __attribute__((ext_vector_type(8)));
typedef _Float16 f16x4 __attribute__((ext_vector_type(4)));
typedef float    f32x4 __attribute__((ext_vector_type(4)));

#define GAMMA_F 0.00390625f

// ---------------------------------------------------------------------------
// prep: fp32 -> fp16 row conversion + row sum-of-squares (for x and sv)
// ---------------------------------------------------------------------------
__global__ __launch_bounds__(256) void prep_rows_kernel(
    const float* __restrict__ src, _Float16* __restrict__ dst,
    float* __restrict__ sq, int nrows)
{
    int lane = threadIdx.x & 63, w = threadIdx.x >> 6;
    int row = blockIdx.x * 4 + w;
    if (row >= nrows) return;
    float4 v = ((const float4*)(src + (size_t)row * 256))[lane];
    f16x4 h;
    h[0] = (_Float16)v.x; h[1] = (_Float16)v.y;
    h[2] = (_Float16)v.z; h[3] = (_Float16)v.w;
    *((f16x4*)(dst + (size_t)row * 256) + lane) = h;
    float ss = v.x*v.x + v.y*v.y + v.z*v.z + v.w*v.w;
#pragma unroll
    for (int off = 32; off; off >>= 1) ss += __shfl_down(ss, off);
    if (lane == 0) sq[row] = ss;
}

__global__ __launch_bounds__(256) void cvt_kernel(
    const float* __restrict__ src, _Float16* __restrict__ dst, int n4)
{
    int i = blockIdx.x * 256 + threadIdx.x;
    if (i < n4) {
        float4 v = ((const float4*)src)[i];
        f16x4 h;
        h[0] = (_Float16)v.x; h[1] = (_Float16)v.y;
        h[2] = (_Float16)v.z; h[3] = (_Float16)v.w;
        ((f16x4*)dst)[i] = h;
    }
}

// init logits with bias (atomic-accumulated by gemm MODE 2)
__global__ __launch_bounds__(256) void init_out_kernel(
    const float* __restrict__ bh, float* __restrict__ out, int n)
{
    int i = blockIdx.x * 256 + threadIdx.x;
    if (i < n) ((float2*)out)[i] = make_float2(bh[0], bh[1]);
}

// ---------------------------------------------------------------------------
// 256x256-tile 8-phase GEMM.
//   MODE 0: C = exp(-g*(e0[m] + e1[n] - 2*acc))
//   MODE 1: C = relu(acc + e0[n])
//   MODE 2: head-fused: v = relu(acc + e0[n]); atomically accumulate
//           out[row][o] += sum_n v * e1[o*1024+n]  (C not written)
// A-frag reads in the post-barrier MFMA zone (lgkm-overlapped); B pre-barrier.
// ks-outer MFMA order (8 independent before 8 dependent partners).
// ---------------------------------------------------------------------------
#define SBAR()  __builtin_amdgcn_s_barrier()
#define AS1 __attribute__((address_space(1)))
#define AS3 __attribute__((address_space(3)))

#define GLD(gptr, dstoff) __builtin_amdgcn_global_load_lds(                    \
    (const AS1 void*)(gptr), (AS3 void*)(ldsb + (dstoff)), 16, 0, 0)

#define STAGE_A(slot, half) do {                                               \
    GLD(aStage + (size_t)(half)*128*K,        (slot)*32768 + (half)*16384 + tb);          \
    GLD(aStage + (size_t)(half)*128*K + 64*K, (slot)*32768 + (half)*16384 + 8192 + tb);   \
} while (0)
#define STAGE_B(slot, half) do {                                               \
    GLD(bStage + (size_t)(half)*128*K,        65536 + (slot)*32768 + (half)*16384 + tb);        \
    GLD(bStage + (size_t)(half)*128*K + 64*K, 65536 + (slot)*32768 + (half)*16384 + 8192 + tb); \
} while (0)

#define READ_A(s, mh) do {                                                     \
    _Pragma("unroll") for (int mi = 0; mi < 4; ++mi) {                         \
        afr[0][mi] = *(const f16x8*)(ldsb + aO0 + (s)*32768 + (mh)*8192 + mi*2048); \
        afr[1][mi] = *(const f16x8*)(ldsb + aO1 + (s)*32768 + (mh)*8192 + mi*2048); \
    } } while (0)

#define READ_B(s, nh) do {                                                     \
    _Pragma("unroll") for (int nb = 0; nb < 2; ++nb) {                         \
        bfr[0][(nh)*2+nb] = *(const f16x8*)(ldsb + bO0 + (s)*32768 + (nh)*4096 + nb*2048); \
        bfr[1][(nh)*2+nb] = *(const f16x8*)(ldsb + bO1 + (s)*32768 + (nh)*4096 + nb*2048); \
    } } while (0)

#define MFMA16(mh, nh) do {                                                    \
    __builtin_amdgcn_s_setprio(1);                                             \
    _Pragma("unroll") for (int ks = 0; ks < 2; ++ks)                           \
    _Pragma("unroll") for (int mi = 0; mi < 4; ++mi)                           \
    _Pragma("unroll") for (int nb = 0; nb < 2; ++nb)                           \
        acc[(mh)*4+mi][(nh)*2+nb] = __builtin_amdgcn_mfma_f32_16x16x32_f16(    \
            afr[ks][mi], bfr[ks][(nh)*2+nb], acc[(mh)*4+mi][(nh)*2+nb], 0,0,0);\
    __builtin_amdgcn_s_setprio(0);                                             \
} while (0)

template <int MODE, int K>
__global__ __launch_bounds__(512, 1) void gemm256_kernel(
    const _Float16* __restrict__ A, const _Float16* __restrict__ B,
    _Float16* __restrict__ C, const float* __restrict__ e0,
    const float* __restrict__ e1, float* __restrict__ outp)
{
    constexpr int KT = K / 64;
    constexpr int NITER = KT / 2;
    __shared__ f16x8 lds[8192];   // A: bytes [0,65536) = 2 slots; B: [65536,131072)
    char* ldsb = (char*)lds;

    const int t    = threadIdx.x;
    const int tb   = t * 16;
    const int lane = t & 63, w = t >> 6;
    const int wr   = w >> 2, wc = w & 3;          // 2 x 4 wave grid
    const int lrow = lane & 15, kq = lane >> 4;

    // XCD-aware bijective swizzle (grid % 8 == 0 by construction)
    int bid  = blockIdx.x;
    int cpx  = (int)(gridDim.x >> 3);
    int lbid = (bid & 7) * cpx + (bid >> 3);
    int bm   = lbid >> 2, bn = lbid & 3;          // NB = 1024/256 = 4
    int rowA0 = bm * 256, rowB0 = bn * 256;

    // LDS-read base byte offsets (everything else is a compile-time imm)
    const int aO0 = ((wr*128 + lrow)*8 + ( kq      ^ (lrow & 7))) * 16;
    const int aO1 = ((wr*128 + lrow)*8 + ((4 + kq) ^ (lrow & 7))) * 16;
    const int bO0 = 65536 + ((wc*64 + lrow)*8 + ( kq      ^ (lrow & 7))) * 16;
    const int bO1 = 65536 + ((wc*64 + lrow)*8 + ((4 + kq) ^ (lrow & 7))) * 16;

    // staging pointers (pre-swizzled source; advance +64 elems per K-tile)
    const int prow = t >> 3;
    const int cg   = (t & 7) ^ (prow & 7);
    const _Float16* aStage = A + (size_t)(rowA0 + prow) * K + cg * 8;
    const _Float16* bStage = B + (size_t)(rowB0 + prow) * K + cg * 8;

    f32x4 acc[8][4];
#pragma unroll
    for (int i = 0; i < 8; ++i)
#pragma unroll
        for (int j = 0; j < 4; ++j) acc[i][j] = (f32x4){0.f, 0.f, 0.f, 0.f};

    f16x8 afr[2][4], bfr[2][4];

    // ---- prologue: tile0 -> slot0, tile1 -> slot1 (16 loads/thread) ----
    STAGE_A(0, 0); STAGE_A(0, 1); STAGE_B(0, 0); STAGE_B(0, 1);
    aStage += 64; bStage += 64;
    STAGE_A(1, 0); STAGE_A(1, 1); STAGE_B(1, 0); STAGE_B(1, 1);
    aStage += 64; bStage += 64;          // A,B now point at tile 2
    asm volatile("s_waitcnt vmcnt(8)" ::: "memory");   // tile0 landed
    SBAR();

    for (int j = 0; j < NITER; ++j) {
        const bool last = (j == NITER - 1);

        // ---- phase 1: tile 2j (slot0), quadrant (m0,n0) ----
        READ_B(0, 0);
        if (j > 0) STAGE_A(1, 0);                      // tile 2j+1 -> slot1
        SBAR();
        READ_A(0, 0);
        MFMA16(0, 0);
        SBAR();
        // ---- phase 2: (m0,n1) ----
        READ_B(0, 1);
        if (j > 0) { STAGE_A(1, 1); aStage += 64; }
        SBAR();
        MFMA16(0, 1);
        SBAR();
        // ---- phase 3: (m1,n0) ----
        if (!last) STAGE_B(0, 0);                      // tile 2j+2 -> slot0
        SBAR();
        READ_A(0, 1);
        MFMA16(1, 0);
        SBAR();
        // ---- phase 4: (m1,n1) + counted vmcnt ----
        if (!last) {
            STAGE_B(0, 1); bStage += 64;
            asm volatile("s_waitcnt vmcnt(4)" ::: "memory");
        } else {
            asm volatile("s_waitcnt vmcnt(0)" ::: "memory");
        }
        SBAR();
        MFMA16(1, 1);
        SBAR();
        // ---- phase 5: tile 2j+1 (slot1), (m0,n0) ----
        READ_B(1, 0);
        if (!last) STAGE_A(0, 0);                      // tile 2j+2 -> slot0
        SBAR();
        READ_A(1, 0);
        MFMA16(0, 0);
        SBAR();
        // ---- phase 6: (m0,n1) ----
        READ_B(1, 1);
        if (!last) { STAGE_A(0, 1); aStage += 64; }
        SBAR();
        MFMA16(0, 1);
        SBAR();
        // ---- phase 7: (m1,n0) ----
        if (!last) STAGE_B(1, 0);                      // tile 2j+3 -> slot1
        SBAR();
        READ_A(1, 1);
        MFMA16(1, 0);
        SBAR();
        // ---- phase 8: (m1,n1) + counted vmcnt ----
        if (!last) {
            STAGE_B(1, 1); bStage += 64;
            asm volatile("s_waitcnt vmcnt(4)" ::: "memory");
        }
        SBAR();
        MFMA16(1, 1);
        SBAR();
    }

    // ---- epilogue ----
    int gr0 = rowA0 + wr * 128;
    int gc0 = rowB0 + wc * 64;
    float ecol[4];
#pragma unroll
    for (int ni = 0; ni < 4; ++ni)
        ecol[ni] = (MODE == 0) ? e1[gc0 + ni * 16 + lrow]
                               : e0[gc0 + ni * 16 + lrow];

    if (MODE == 2) {
        // head-fused: per-row partial logits, lrow-group reduce, atomic accumulate
        float wh0[4], wh1[4];
#pragma unroll
        for (int ni = 0; ni < 4; ++ni) {
            int col = gc0 + ni * 16 + lrow;
            wh0[ni] = e1[col];
            wh1[ni] = e1[1024 + col];
        }
#pragma unroll
        for (int mi = 0; mi < 8; ++mi) {
#pragma unroll
            for (int jj = 0; jj < 4; ++jj) {
                int row = gr0 + mi * 16 + kq * 4 + jj;
                float p0 = 0.f, p1 = 0.f;
#pragma unroll
                for (int ni = 0; ni < 4; ++ni) {
                    float v = fmaxf(acc[mi][ni][jj] + ecol[ni], 0.f);
                    p0 = fmaf(v, wh0[ni], p0);
                    p1 = fmaf(v, wh1[ni], p1);
                }
#pragma unroll
                for (int off = 1; off < 16; off <<= 1) {
                    p0 += __shfl_xor(p0, off);
                    p1 += __shfl_xor(p1, off);
                }
                if (lrow == 0) {
                    atomicAdd(outp + (size_t)row * 2 + 0, p0);
                    atomicAdd(outp + (size_t)row * 2 + 1, p1);
                }
            }
        }
        return;
    }

#pragma unroll
    for (int mi = 0; mi < 8; ++mi) {
#pragma unroll
        for (int jj = 0; jj < 4; ++jj) {
            int row = gr0 + mi * 16 + kq * 4 + jj;
            float xr = (MODE == 0) ? e0[row] : 0.f;
            size_t base = (size_t)row * 1024 + gc0 + lrow;
#pragma unroll
            for (int ni = 0; ni < 4; ++ni) {
                float v = acc[mi][ni][jj];
                if (MODE == 0) {
                    v = __expf(-GAMMA_F * (xr + ecol[ni] - 2.f * v));
                } else {
                    v += ecol[ni];
                    v = fmaxf(v, 0.f);
                }
                C[base + (size_t)ni * 16] = (_Float16)v;
            }
        }
    }
}

// ---------------------------------------------------------------------------
extern "C" void kernel_launch(void* const* d_in, const int* in_sizes, int n_in,
                              void* d_out, int out_size, void* d_ws, size_t ws_size,
                              hipStream_t stream)
{
    const float* x  = (const float*)d_in[0];
    const float* sv = (const float*)d_in[1];
    const float* W1 = (const float*)d_in[2];
    const float* b1 = (const float*)d_in[3];
    const float* W2 = (const float*)d_in[4];
    const float* b2 = (const float*)d_in[5];
    const float* Wh = (const float*)d_in[6];
    const float* bh = (const float*)d_in[7];
    float* out = (float*)d_out;
    char* ws = (char*)d_ws;

    // ---- persistent region (~4.6 MB) ----
    constexpr size_t OFF_SV = 0;
    constexpr size_t OFF_W1 = OFF_SV + 524288;
    constexpr size_t OFF_W2 = OFF_W1 + 2097152;
    constexpr size_t OFF_WH = OFF_W2 + 2097152;         // 8 KB Wh f32 (copy not needed; use d_in)
    constexpr size_t OFF_S2 = OFF_WH + 8192;
    constexpr size_t PERSIST = OFF_S2 + 4096;

    _Float16* svf = (_Float16*)(ws + OFF_SV);
    _Float16* w1f = (_Float16*)(ws + OFF_W1);
    _Float16* w2f = (_Float16*)(ws + OFF_W2);
    float*    s2v = (float*)(ws + OFF_S2);

    // ---- adaptive batch chunking ----
    int Bc = 65536;
    while (Bc > 256 && PERSIST + (size_t)Bc * 4100ULL > ws_size) Bc >>= 1;

    char* chunk_base = ws + PERSIST;
    _Float16* kb  = (_Float16*)chunk_base;                        // Bc x 1024 fp16
    _Float16* h1b = (_Float16*)(chunk_base + (size_t)Bc * 2048);  // Bc x 1024 fp16
    _Float16* xf  = h1b;                                          // overlapped (dies before h1 written)
    float*    x2v = (float*)(chunk_base + (size_t)Bc * 4096);

    prep_rows_kernel<<<1024 / 4, 256, 0, stream>>>(sv, svf, s2v, 1024);
    cvt_kernel<<<1024, 256, 0, stream>>>(W1, w1f, 262144);
    cvt_kernel<<<1024, 256, 0, stream>>>(W2, w2f, 262144);
    init_out_kernel<<<256, 256, 0, stream>>>(bh, out, 65536);

    int nchunks = 65536 / Bc;
    int ggrid   = (Bc / 256) * 4;
    for (int c = 0; c < nchunks; ++c) {
        const float* xc = x + (size_t)c * Bc * 256;
        prep_rows_kernel<<<Bc / 4, 256, 0, stream>>>(xc, xf, x2v, Bc);
        // k = exp(-g*(x2 + s2 - 2*x.sv))
        gemm256_kernel<0, 256><<<ggrid, 512, 0, stream>>>(xf, svf, kb, x2v, s2v, nullptr);
        // h1 = relu(k @ W1^T + b1)
        gemm256_kernel<1, 1024><<<ggrid, 512, 0, stream>>>(kb, w1f, h1b, b1, nullptr, nullptr);
        // logits += head(relu(h1 @ W2^T + b2))  [h2 never materialized]
        gemm256_kernel<2, 1024><<<ggrid, 512, 0, stream>>>(h1b, w2f, kb, b2, Wh,
                                                           out + (size_t)c * Bc * 2);
    }
}

// Round 9
// 391.730 us; speedup vs baseline: 1.1656x; 1.1656x over previous
//
#include <hip/hip_runtime.h>

typedef _Float16 f16x8 __attribute__((ext_vector_type(8)));
typedef _Float16 f16x4 __attribute__((ext_vector_type(4)));
typedef float    f32x4 __attribute__((ext_vector_type(4)));

#define GAMMA_F 0.00390625f

// ---------------------------------------------------------------------------
// prep: fp32 -> fp16 row conversion + row sum-of-squares (for x and sv)
// ---------------------------------------------------------------------------
__global__ __launch_bounds__(256) void prep_rows_kernel(
    const float* __restrict__ src, _Float16* __restrict__ dst,
    float* __restrict__ sq, int nrows)
{
    int lane = threadIdx.x & 63, w = threadIdx.x >> 6;
    int row = blockIdx.x * 4 + w;
    if (row >= nrows) return;
    float4 v = ((const float4*)(src + (size_t)row * 256))[lane];
    f16x4 h;
    h[0] = (_Float16)v.x; h[1] = (_Float16)v.y;
    h[2] = (_Float16)v.z; h[3] = (_Float16)v.w;
    *((f16x4*)(dst + (size_t)row * 256) + lane) = h;
    float ss = v.x*v.x + v.y*v.y + v.z*v.z + v.w*v.w;
#pragma unroll
    for (int off = 32; off; off >>= 1) ss += __shfl_down(ss, off);
    if (lane == 0) sq[row] = ss;
}

__global__ __launch_bounds__(256) void cvt_kernel(
    const float* __restrict__ src, _Float16* __restrict__ dst, int n4)
{
    int i = blockIdx.x * 256 + threadIdx.x;
    if (i < n4) {
        float4 v = ((const float4*)src)[i];
        f16x4 h;
        h[0] = (_Float16)v.x; h[1] = (_Float16)v.y;
        h[2] = (_Float16)v.z; h[3] = (_Float16)v.w;
        ((f16x4*)dst)[i] = h;
    }
}

// ---------------------------------------------------------------------------
// 256x256-tile 8-phase GEMM, asm-staged.
// Staging via inline-asm global_load_lds_dwordx4 (invisible to the compiler's
// memory-dependence model) so the ONLY vmem waits in the K-loop are our
// counted vmcnt(8/4/0) asms — the compiler cannot insert per-phase vmcnt(0)
// drains against aliasing ds_reads (the suspected 900-cyc/phase stall,
// r3-r7 all pinned at 33-35% MfmaUtil regardless of schedule).
// M0 = wave-uniform LDS byte base (readfirstlane), restored to -1 in-blob.
// RFENCE (empty memory-clobber asm) at each phase head stops CSE/hoist of
// the now-unordered ds_reads; ledger: tile lands >=1 counted-vmcnt + barrier
// before first read (in-order vmcnt retirement).
//   MODE 0: C = exp(-g*(e0[m] + e1[n] - 2*acc))
//   MODE 1: C = relu(acc + e0[n])
// ---------------------------------------------------------------------------
#define SBAR()   __builtin_amdgcn_s_barrier()
#define RFENCE() asm volatile("" ::: "memory")

#define GLDA(gptr, uoff)                                                       \
    asm volatile("s_mov_b32 m0, %1\n\t"                                        \
                 "global_load_lds_dwordx4 %0, off\n\t"                         \
                 "s_mov_b32 m0, -1"                                            \
                 :: "v"((const void*)(gptr)), "s"(uoff))

#define UOF(x) __builtin_amdgcn_readfirstlane((x) + wb)

#define STAGE_A(slot, half) do {                                               \
    GLDA(aStage + (size_t)(half)*128*K,                                        \
         UOF((slot)*32768 + (half)*16384));                                    \
    GLDA(aStage + (size_t)(half)*128*K + (size_t)64*K,                         \
         UOF((slot)*32768 + (half)*16384 + 8192));                             \
} while (0)
#define STAGE_B(slot, half) do {                                               \
    GLDA(bStage + (size_t)(half)*128*K,                                        \
         UOF(65536 + (slot)*32768 + (half)*16384));                            \
    GLDA(bStage + (size_t)(half)*128*K + (size_t)64*K,                         \
         UOF(65536 + (slot)*32768 + (half)*16384 + 8192));                     \
} while (0)

#define READ_A(s, mh) do {                                                     \
    _Pragma("unroll") for (int mi = 0; mi < 4; ++mi) {                         \
        afr[0][mi] = *(const f16x8*)(ldsb + aO0 + (s)*32768 + (mh)*8192 + mi*2048); \
        afr[1][mi] = *(const f16x8*)(ldsb + aO1 + (s)*32768 + (mh)*8192 + mi*2048); \
    } } while (0)

#define READ_B(s, nh) do {                                                     \
    _Pragma("unroll") for (int nb = 0; nb < 2; ++nb) {                         \
        bfr[0][(nh)*2+nb] = *(const f16x8*)(ldsb + bO0 + (s)*32768 + (nh)*4096 + nb*2048); \
        bfr[1][(nh)*2+nb] = *(const f16x8*)(ldsb + bO1 + (s)*32768 + (nh)*4096 + nb*2048); \
    } } while (0)

#define MFMA16(mh, nh) do {                                                    \
    __builtin_amdgcn_s_setprio(1);                                             \
    _Pragma("unroll") for (int mi = 0; mi < 4; ++mi)                           \
    _Pragma("unroll") for (int nb = 0; nb < 2; ++nb)                           \
    _Pragma("unroll") for (int ks = 0; ks < 2; ++ks)                           \
        acc[(mh)*4+mi][(nh)*2+nb] = __builtin_amdgcn_mfma_f32_16x16x32_f16(    \
            afr[ks][mi], bfr[ks][(nh)*2+nb], acc[(mh)*4+mi][(nh)*2+nb], 0,0,0);\
    __builtin_amdgcn_s_setprio(0);                                             \
} while (0)

template <int MODE, int K>
__global__ __launch_bounds__(512, 1) void gemm256_kernel(
    const _Float16* __restrict__ A, const _Float16* __restrict__ B,
    _Float16* __restrict__ C, const float* __restrict__ e0,
    const float* __restrict__ e1)
{
    constexpr int KT = K / 64;
    constexpr int NITER = KT / 2;
    __shared__ f16x8 lds[8192];   // A: bytes [0,65536) = 2 slots; B: [65536,131072)
    char* ldsb = (char*)lds;

    const int t    = threadIdx.x;
    const int lane = t & 63, w = t >> 6;
    const int wb   = w << 10;                     // wave-uniform LDS base part
    const int wr   = w >> 2, wc = w & 3;          // 2 x 4 wave grid
    const int lrow = lane & 15, kq = lane >> 4;

    // keep `lds` formally stored-to (reads are fed by asm-invisible staging;
    // without this the compiler may fold loads of a never-stored array)
    int poison = 0;
    asm volatile("" : "+v"(poison));
    if (poison) lds[0] = f16x8{};

    // XCD-aware bijective swizzle (grid % 8 == 0 by construction)
    int bid  = blockIdx.x;
    int cpx  = (int)(gridDim.x >> 3);
    int lbid = (bid & 7) * cpx + (bid >> 3);
    int bm   = lbid >> 2, bn = lbid & 3;          // NB = 1024/256 = 4
    int rowA0 = bm * 256, rowB0 = bn * 256;

    // LDS-read base byte offsets (everything else is a compile-time imm)
    const int aO0 = ((wr*128 + lrow)*8 + ( kq      ^ (lrow & 7))) * 16;
    const int aO1 = ((wr*128 + lrow)*8 + ((4 + kq) ^ (lrow & 7))) * 16;
    const int bO0 = 65536 + ((wc*64 + lrow)*8 + ( kq      ^ (lrow & 7))) * 16;
    const int bO1 = 65536 + ((wc*64 + lrow)*8 + ((4 + kq) ^ (lrow & 7))) * 16;

    // staging pointers (pre-swizzled source; advance +64 elems per K-tile)
    const int prow = t >> 3;
    const int cg   = (t & 7) ^ (prow & 7);
    const _Float16* aStage = A + (size_t)(rowA0 + prow) * K + cg * 8;
    const _Float16* bStage = B + (size_t)(rowB0 + prow) * K + cg * 8;

    f32x4 acc[8][4];
#pragma unroll
    for (int i = 0; i < 8; ++i)
#pragma unroll
        for (int j = 0; j < 4; ++j) acc[i][j] = (f32x4){0.f, 0.f, 0.f, 0.f};

    f16x8 afr[2][4], bfr[2][4];

    // ---- prologue: tile0 -> slot0, tile1 -> slot1 (16 loads/thread) ----
    STAGE_A(0, 0); STAGE_A(0, 1); STAGE_B(0, 0); STAGE_B(0, 1);
    aStage += 64; bStage += 64;
    STAGE_A(1, 0); STAGE_A(1, 1); STAGE_B(1, 0); STAGE_B(1, 1);
    aStage += 64; bStage += 64;          // A,B now point at tile 2
    asm volatile("s_waitcnt vmcnt(8)" ::: "memory");   // tile0 landed
    SBAR();

    for (int j = 0; j < NITER; ++j) {
        const bool last = (j == NITER - 1);

        // ---- phase 1: tile 2j (slot0), quadrant (m0,n0) ----
        RFENCE();
        READ_A(0, 0); READ_B(0, 0);
        if (j > 0) STAGE_A(1, 0);                      // tile 2j+1 -> slot1
        SBAR();
        MFMA16(0, 0);
        SBAR();
        // ---- phase 2: (m0,n1) ----
        RFENCE();
        READ_B(0, 1);
        if (j > 0) { STAGE_A(1, 1); aStage += 64; }
        SBAR();
        MFMA16(0, 1);
        SBAR();
        // ---- phase 3: (m1,n0) ----
        RFENCE();
        READ_A(0, 1);
        if (!last) STAGE_B(0, 0);                      // tile 2j+2 -> slot0
        SBAR();
        MFMA16(1, 0);
        SBAR();
        // ---- phase 4: (m1,n1) + counted vmcnt ----
        if (!last) {
            STAGE_B(0, 1); bStage += 64;
            asm volatile("s_waitcnt vmcnt(4)" ::: "memory");
        } else {
            asm volatile("s_waitcnt vmcnt(0)" ::: "memory");
        }
        SBAR();
        MFMA16(1, 1);
        SBAR();
        // ---- phase 5: tile 2j+1 (slot1), (m0,n0) ----
        RFENCE();
        READ_A(1, 0); READ_B(1, 0);
        if (!last) STAGE_A(0, 0);                      // tile 2j+2 -> slot0
        SBAR();
        MFMA16(0, 0);
        SBAR();
        // ---- phase 6: (m0,n1) ----
        RFENCE();
        READ_B(1, 1);
        if (!last) { STAGE_A(0, 1); aStage += 64; }
        SBAR();
        MFMA16(0, 1);
        SBAR();
        // ---- phase 7: (m1,n0) ----
        RFENCE();
        READ_A(1, 1);
        if (!last) STAGE_B(1, 0);                      // tile 2j+3 -> slot1
        SBAR();
        MFMA16(1, 0);
        SBAR();
        // ---- phase 8: (m1,n1) + counted vmcnt ----
        if (!last) {
            STAGE_B(1, 1); bStage += 64;
            asm volatile("s_waitcnt vmcnt(4)" ::: "memory");
        }
        SBAR();
        MFMA16(1, 1);
        SBAR();
    }

    // ---- epilogue ----
    int gr0 = rowA0 + wr * 128;
    int gc0 = rowB0 + wc * 64;
    float ecol[4];
#pragma unroll
    for (int ni = 0; ni < 4; ++ni)
        ecol[ni] = (MODE == 0) ? e1[gc0 + ni * 16 + lrow]
                               : e0[gc0 + ni * 16 + lrow];
#pragma unroll
    for (int mi = 0; mi < 8; ++mi) {
#pragma unroll
        for (int jj = 0; jj < 4; ++jj) {
            int row = gr0 + mi * 16 + kq * 4 + jj;
            float xr = (MODE == 0) ? e0[row] : 0.f;
            size_t base = (size_t)row * 1024 + gc0 + lrow;
#pragma unroll
            for (int ni = 0; ni < 4; ++ni) {
                float v = acc[mi][ni][jj];
                if (MODE == 0) {
                    v = __expf(-GAMMA_F * (xr + ecol[ni] - 2.f * v));
                } else {
                    v += ecol[ni];
                    v = fmaxf(v, 0.f);
                }
                C[base + (size_t)ni * 16] = (_Float16)v;
            }
        }
    }
}

// ---------------------------------------------------------------------------
// head: out[b][o] = sum_s h2[b][s]*Wh[o][s] + bh[o], o in {0,1}
// ---------------------------------------------------------------------------
__global__ __launch_bounds__(256) void head_kernel(
    const _Float16* __restrict__ h2, const float* __restrict__ Wh,
    const float* __restrict__ bh, float* __restrict__ out)
{
    int lane = threadIdx.x & 63, w = threadIdx.x >> 6;
    int row = blockIdx.x * 4 + w;
    const _Float16* hp = h2 + (size_t)row * 1024;
    float s0 = 0.f, s1 = 0.f;
#pragma unroll
    for (int i = 0; i < 2; ++i) {
        int base = (i * 64 + lane) * 8;
        f16x8 hv = *(const f16x8*)(hp + base);
#pragma unroll
        for (int j = 0; j < 8; ++j) {
            float hj = (float)hv[j];
            s0 = fmaf(hj, Wh[base + j], s0);
            s1 = fmaf(hj, Wh[1024 + base + j], s1);
        }
    }
#pragma unroll
    for (int off = 32; off; off >>= 1) {
        s0 += __shfl_down(s0, off);
        s1 += __shfl_down(s1, off);
    }
    if (lane == 0) {
        out[(size_t)row * 2 + 0] = s0 + bh[0];
        out[(size_t)row * 2 + 1] = s1 + bh[1];
    }
}

// ---------------------------------------------------------------------------
extern "C" void kernel_launch(void* const* d_in, const int* in_sizes, int n_in,
                              void* d_out, int out_size, void* d_ws, size_t ws_size,
                              hipStream_t stream)
{
    const float* x  = (const float*)d_in[0];
    const float* sv = (const float*)d_in[1];
    const float* W1 = (const float*)d_in[2];
    const float* b1 = (const float*)d_in[3];
    const float* W2 = (const float*)d_in[4];
    const float* b2 = (const float*)d_in[5];
    const float* Wh = (const float*)d_in[6];
    const float* bh = (const float*)d_in[7];
    float* out = (float*)d_out;
    char* ws = (char*)d_ws;

    // ---- persistent region (~4.6 MB) ----
    constexpr size_t OFF_SV = 0;
    constexpr size_t OFF_W1 = OFF_SV + 524288;
    constexpr size_t OFF_W2 = OFF_W1 + 2097152;
    constexpr size_t OFF_S2 = OFF_W2 + 2097152;
    constexpr size_t PERSIST = OFF_S2 + 4096;

    _Float16* svf = (_Float16*)(ws + OFF_SV);
    _Float16* w1f = (_Float16*)(ws + OFF_W1);
    _Float16* w2f = (_Float16*)(ws + OFF_W2);
    float*    s2v = (float*)(ws + OFF_S2);

    // ---- adaptive batch chunking ----
    int Bc = 65536;
    while (Bc > 256 && PERSIST + (size_t)Bc * 4100ULL > ws_size) Bc >>= 1;

    char* chunk_base = ws + PERSIST;
    _Float16* kb  = (_Float16*)chunk_base;                        // Bc x 1024 fp16
    _Float16* h1b = (_Float16*)(chunk_base + (size_t)Bc * 2048);  // Bc x 1024 fp16
    _Float16* xf  = h1b;                                          // overlapped (dies before h1 written)
    float*    x2v = (float*)(chunk_base + (size_t)Bc * 4096);

    prep_rows_kernel<<<1024 / 4, 256, 0, stream>>>(sv, svf, s2v, 1024);
    cvt_kernel<<<1024, 256, 0, stream>>>(W1, w1f, 262144);
    cvt_kernel<<<1024, 256, 0, stream>>>(W2, w2f, 262144);

    int nchunks = 65536 / Bc;
    int ggrid   = (Bc / 256) * 4;
    for (int c = 0; c < nchunks; ++c) {
        const float* xc = x + (size_t)c * Bc * 256;
        prep_rows_kernel<<<Bc / 4, 256, 0, stream>>>(xc, xf, x2v, Bc);
        gemm256_kernel<0, 256><<<ggrid, 512, 0, stream>>>(xf, svf, kb, x2v, s2v);
        gemm256_kernel<1, 1024><<<ggrid, 512, 0, stream>>>(kb, w1f, h1b, b1, nullptr);
        gemm256_kernel<1, 1024><<<ggrid, 512, 0, stream>>>(h1b, w2f, kb, b2, nullptr);
        head_kernel<<<Bc / 4, 256, 0, stream>>>(kb, Wh, bh, out + (size_t)c * Bc * 2);
    }
}

// Round 10
// 387.146 us; speedup vs baseline: 1.1794x; 1.0118x over previous
//
#include <hip/hip_runtime.h>

typedef _Float16 f16x8 __attribute__((ext_vector_type(8)));
typedef _Float16 f16x4 __attribute__((ext_vector_type(4)));
typedef float    f32x4 __attribute__((ext_vector_type(4)));

#define GAMMA_F 0.00390625f

// ---------------------------------------------------------------------------
// prep: fp32 -> fp16 row conversion + row sum-of-squares (for x and sv)
// ---------------------------------------------------------------------------
__global__ __launch_bounds__(256) void prep_rows_kernel(
    const float* __restrict__ src, _Float16* __restrict__ dst,
    float* __restrict__ sq, int nrows)
{
    int lane = threadIdx.x & 63, w = threadIdx.x >> 6;
    int row = blockIdx.x * 4 + w;
    if (row >= nrows) return;
    float4 v = ((const float4*)(src + (size_t)row * 256))[lane];
    f16x4 h;
    h[0] = (_Float16)v.x; h[1] = (_Float16)v.y;
    h[2] = (_Float16)v.z; h[3] = (_Float16)v.w;
    *((f16x4*)(dst + (size_t)row * 256) + lane) = h;
    float ss = v.x*v.x + v.y*v.y + v.z*v.z + v.w*v.w;
#pragma unroll
    for (int off = 32; off; off >>= 1) ss += __shfl_down(ss, off);
    if (lane == 0) sq[row] = ss;
}

__global__ __launch_bounds__(256) void cvt_kernel(
    const float* __restrict__ src, _Float16* __restrict__ dst, int n4)
{
    int i = blockIdx.x * 256 + threadIdx.x;
    if (i < n4) {
        float4 v = ((const float4*)src)[i];
        f16x4 h;
        h[0] = (_Float16)v.x; h[1] = (_Float16)v.y;
        h[2] = (_Float16)v.z; h[3] = (_Float16)v.w;
        ((f16x4*)dst)[i] = h;
    }
}

// ---------------------------------------------------------------------------
// 256x256-tile 8-phase GEMM, asm-staged, ks-split reads.
// Per phase: pre-barrier = ks0 frag reads + 1 stage; post-barrier = issue ks1
// frag reads (LDS service hides under MFMA), 8 MFMA(ks0), 8 MFMA(ks1).
// B frags read once per tile, kept live across their 2 consuming phases.
// 8 persistent staging pointer pairs; all frag/LDS offsets compile-time.
//   MODE 0: C = exp(-g*(e0[m] + e1[n] - 2*acc))
//   MODE 1: C = relu(acc + e0[n])
// ---------------------------------------------------------------------------
#define SBAR()   __builtin_amdgcn_s_barrier()
#define RFENCE() asm volatile("" ::: "memory")

#define GLDA(gptr, uoff)                                                       \
    asm volatile("s_mov_b32 m0, %1\n\t"                                        \
                 "global_load_lds_dwordx4 %0, off\n\t"                         \
                 "s_mov_b32 m0, -1"                                            \
                 :: "v"((const void*)(gptr)), "s"(uoff))

#define UOF(x) __builtin_amdgcn_readfirstlane((x) + wb)

// stage half h (rows h*128 .. h*128+127) of the CURRENT A/B tile into slot s
#define STA(s, h) do {                                                         \
    GLDA(aP##h##0, UOF((s)*32768 + (h)*16384));                                \
    GLDA(aP##h##1, UOF((s)*32768 + (h)*16384 + 8192));                         \
} while (0)
#define STB(s, h) do {                                                         \
    GLDA(bP##h##0, UOF(65536 + (s)*32768 + (h)*16384));                        \
    GLDA(bP##h##1, UOF(65536 + (s)*32768 + (h)*16384 + 8192));                 \
} while (0)
#define ADV_A() do { aP00+=64; aP01+=64; aP10+=64; aP11+=64; } while (0)
#define ADV_B() do { bP00+=64; bP01+=64; bP10+=64; bP11+=64; } while (0)

#define PRE_A(s, mh) do { _Pragma("unroll") for (int mi = 0; mi < 4; ++mi)     \
    a0f[mi] = *(const f16x8*)(ldsb + aO0 + (s)*32768 + (mh)*8192 + mi*2048);   \
} while (0)
#define POST_A(s, mh) do { _Pragma("unroll") for (int mi = 0; mi < 4; ++mi)    \
    a1f[mi] = *(const f16x8*)(ldsb + aO1 + (s)*32768 + (mh)*8192 + mi*2048);   \
} while (0)
#define PRE_BA(s, nh) do { _Pragma("unroll") for (int nb = 0; nb < 2; ++nb)    \
    bA0[nb] = *(const f16x8*)(ldsb + bO0 + (s)*32768 + (nh)*4096 + nb*2048);   \
} while (0)
#define POST_BA(s, nh) do { _Pragma("unroll") for (int nb = 0; nb < 2; ++nb)   \
    bA1[nb] = *(const f16x8*)(ldsb + bO1 + (s)*32768 + (nh)*4096 + nb*2048);   \
} while (0)
#define PRE_BB(s, nh) do { _Pragma("unroll") for (int nb = 0; nb < 2; ++nb)    \
    bB0[nb] = *(const f16x8*)(ldsb + bO0 + (s)*32768 + (nh)*4096 + nb*2048);   \
} while (0)
#define POST_BB(s, nh) do { _Pragma("unroll") for (int nb = 0; nb < 2; ++nb)   \
    bB1[nb] = *(const f16x8*)(ldsb + bO1 + (s)*32768 + (nh)*4096 + nb*2048);   \
} while (0)

#define MFMA8(af, bf, mh, nh) do {                                             \
    _Pragma("unroll") for (int mi = 0; mi < 4; ++mi)                           \
    _Pragma("unroll") for (int nb = 0; nb < 2; ++nb)                           \
        acc[(mh)*4+mi][(nh)*2+nb] = __builtin_amdgcn_mfma_f32_16x16x32_f16(    \
            af[mi], bf[nb], acc[(mh)*4+mi][(nh)*2+nb], 0, 0, 0);               \
} while (0)

template <int MODE, int K>
__global__ __launch_bounds__(512, 1) void gemm256_kernel(
    const _Float16* __restrict__ A, const _Float16* __restrict__ B,
    _Float16* __restrict__ C, const float* __restrict__ e0,
    const float* __restrict__ e1)
{
    constexpr int KT = K / 64;
    constexpr int NITER = KT / 2;
    __shared__ f16x8 lds[8192];   // A bytes [0,65536): 2 slots; B: [65536,131072)
    char* ldsb = (char*)lds;

    const int t    = threadIdx.x;
    const int lane = t & 63, w = t >> 6;
    const int wb   = w << 10;                     // wave-uniform LDS base part
    const int wr   = w >> 2, wc = w & 3;          // 2 x 4 wave grid
    const int lrow = lane & 15, kq = lane >> 4;

    // keep lds formally stored-to (reads fed by asm-invisible staging)
    int poison = 0;
    asm volatile("" : "+v"(poison));
    if (poison) lds[0] = f16x8{};

    // XCD-aware bijective swizzle (grid % 8 == 0 by construction)
    int bid  = blockIdx.x;
    int cpx  = (int)(gridDim.x >> 3);
    int lbid = (bid & 7) * cpx + (bid >> 3);
    int bm   = lbid >> 2, bn = lbid & 3;          // NB = 1024/256 = 4
    int rowA0 = bm * 256, rowB0 = bn * 256;

    // LDS-read base byte offsets
    const int aO0 = ((wr*128 + lrow)*8 + ( kq      ^ (lrow & 7))) * 16;
    const int aO1 = ((wr*128 + lrow)*8 + ((4 + kq) ^ (lrow & 7))) * 16;
    const int bO0 = 65536 + ((wc*64 + lrow)*8 + ( kq      ^ (lrow & 7))) * 16;
    const int bO1 = 65536 + ((wc*64 + lrow)*8 + ((4 + kq) ^ (lrow & 7))) * 16;

    // persistent staging pointers: 4 row-blocks x {A,B}, advance +64 elem/tile
    const int prow = t >> 3;
    const int cg   = (t & 7) ^ (prow & 7);
    const _Float16* aP00 = A + (size_t)(rowA0 + prow      ) * K + cg * 8;
    const _Float16* aP01 = aP00 + (size_t) 64 * K;
    const _Float16* aP10 = aP00 + (size_t)128 * K;
    const _Float16* aP11 = aP00 + (size_t)192 * K;
    const _Float16* bP00 = B + (size_t)(rowB0 + prow      ) * K + cg * 8;
    const _Float16* bP01 = bP00 + (size_t) 64 * K;
    const _Float16* bP10 = bP00 + (size_t)128 * K;
    const _Float16* bP11 = bP00 + (size_t)192 * K;

    f32x4 acc[8][4];
#pragma unroll
    for (int i = 0; i < 8; ++i)
#pragma unroll
        for (int j = 0; j < 4; ++j) acc[i][j] = (f32x4){0.f, 0.f, 0.f, 0.f};

    f16x8 a0f[4], a1f[4], bA0[2], bA1[2], bB0[2], bB1[2];

    // ---- prologue: tile0 -> slot0, tile1 -> slot1 ----
    STA(0,0); STA(0,1); STB(0,0); STB(0,1); ADV_A(); ADV_B();
    STA(1,0); STA(1,1); STB(1,0); STB(1,1); ADV_A(); ADV_B();   // now at tile2
    asm volatile("s_waitcnt vmcnt(8)" ::: "memory");            // tile0 landed
    SBAR();

    for (int j = 0; j < NITER; ++j) {
        const bool last = (j == NITER - 1);

        // ---- phase 1: slot0, quad (0,0) ----
        RFENCE();
        PRE_A(0, 0); PRE_BA(0, 0);
        if (j > 0) STA(1, 0);                       // tile 2j+1 A-half0 -> s1
        SBAR();
        POST_A(0, 0); POST_BA(0, 0);
        __builtin_amdgcn_s_setprio(1);
        MFMA8(a0f, bA0, 0, 0); MFMA8(a1f, bA1, 0, 0);
        __builtin_amdgcn_s_setprio(0);
        SBAR();
        // ---- phase 2: (0,1) ----
        RFENCE();
        PRE_BB(0, 1);
        if (j > 0) { STA(1, 1); ADV_A(); }          // A now at tile 2j+2
        SBAR();
        POST_BB(0, 1);
        __builtin_amdgcn_s_setprio(1);
        MFMA8(a0f, bB0, 0, 1); MFMA8(a1f, bB1, 0, 1);
        __builtin_amdgcn_s_setprio(0);
        SBAR();
        // ---- phase 3: (1,0) ----
        RFENCE();
        PRE_A(0, 1);
        if (!last) STB(0, 0);                       // tile 2j+2 B-half0 -> s0
        SBAR();
        POST_A(0, 1);
        __builtin_amdgcn_s_setprio(1);
        MFMA8(a0f, bA0, 1, 0); MFMA8(a1f, bA1, 1, 0);
        __builtin_amdgcn_s_setprio(0);
        SBAR();
        // ---- phase 4: (1,1) + counted vmcnt ----
        RFENCE();
        if (!last) {
            STB(0, 1); ADV_B();                     // B now at tile 2j+3
            asm volatile("s_waitcnt vmcnt(4)" ::: "memory");
        } else {
            asm volatile("s_waitcnt vmcnt(0)" ::: "memory");
        }
        SBAR();
        __builtin_amdgcn_s_setprio(1);
        MFMA8(a0f, bB0, 1, 1); MFMA8(a1f, bB1, 1, 1);
        __builtin_amdgcn_s_setprio(0);
        SBAR();
        // ---- phase 5: slot1, quad (0,0) ----
        RFENCE();
        PRE_A(1, 0); PRE_BA(1, 0);
        if (!last) STA(0, 0);                       // tile 2j+2 A-half0 -> s0
        SBAR();
        POST_A(1, 0); POST_BA(1, 0);
        __builtin_amdgcn_s_setprio(1);
        MFMA8(a0f, bA0, 0, 0); MFMA8(a1f, bA1, 0, 0);
        __builtin_amdgcn_s_setprio(0);
        SBAR();
        // ---- phase 6: (0,1) ----
        RFENCE();
        PRE_BB(1, 1);
        if (!last) { STA(0, 1); ADV_A(); }          // A now at tile 2j+3
        SBAR();
        POST_BB(1, 1);
        __builtin_amdgcn_s_setprio(1);
        MFMA8(a0f, bB0, 0, 1); MFMA8(a1f, bB1, 0, 1);
        __builtin_amdgcn_s_setprio(0);
        SBAR();
        // ---- phase 7: (1,0) ----
        RFENCE();
        PRE_A(1, 1);
        if (!last) STB(1, 0);                       // tile 2j+3 B-half0 -> s1
        SBAR();
        POST_A(1, 1);
        __builtin_amdgcn_s_setprio(1);
        MFMA8(a0f, bA0, 1, 0); MFMA8(a1f, bA1, 1, 0);
        __builtin_amdgcn_s_setprio(0);
        SBAR();
        // ---- phase 8: (1,1) + counted vmcnt ----
        RFENCE();
        if (!last) {
            STB(1, 1); ADV_B();                     // B now at tile 2j+4
            asm volatile("s_waitcnt vmcnt(4)" ::: "memory");
        }
        SBAR();
        __builtin_amdgcn_s_setprio(1);
        MFMA8(a0f, bB0, 1, 1); MFMA8(a1f, bB1, 1, 1);
        __builtin_amdgcn_s_setprio(0);
        SBAR();
    }

    // ---- epilogue ----
    int gr0 = rowA0 + wr * 128;
    int gc0 = rowB0 + wc * 64;
    float ecol[4];
#pragma unroll
    for (int ni = 0; ni < 4; ++ni)
        ecol[ni] = (MODE == 0) ? e1[gc0 + ni * 16 + lrow]
                               : e0[gc0 + ni * 16 + lrow];
#pragma unroll
    for (int mi = 0; mi < 8; ++mi) {
#pragma unroll
        for (int jj = 0; jj < 4; ++jj) {
            int row = gr0 + mi * 16 + kq * 4 + jj;
            float xr = (MODE == 0) ? e0[row] : 0.f;
            size_t base = (size_t)row * 1024 + gc0 + lrow;
#pragma unroll
            for (int ni = 0; ni < 4; ++ni) {
                float v = acc[mi][ni][jj];
                if (MODE == 0) {
                    v = __expf(-GAMMA_F * (xr + ecol[ni] - 2.f * v));
                } else {
                    v += ecol[ni];
                    v = fmaxf(v, 0.f);
                }
                C[base + (size_t)ni * 16] = (_Float16)v;
            }
        }
    }
}

// ---------------------------------------------------------------------------
// head: out[b][o] = sum_s h2[b][s]*Wh[o][s] + bh[o], o in {0,1}
// ---------------------------------------------------------------------------
__global__ __launch_bounds__(256) void head_kernel(
    const _Float16* __restrict__ h2, const float* __restrict__ Wh,
    const float* __restrict__ bh, float* __restrict__ out)
{
    int lane = threadIdx.x & 63, w = threadIdx.x >> 6;
    int row = blockIdx.x * 4 + w;
    const _Float16* hp = h2 + (size_t)row * 1024;
    float s0 = 0.f, s1 = 0.f;
#pragma unroll
    for (int i = 0; i < 2; ++i) {
        int base = (i * 64 + lane) * 8;
        f16x8 hv = *(const f16x8*)(hp + base);
#pragma unroll
        for (int j = 0; j < 8; ++j) {
            float hj = (float)hv[j];
            s0 = fmaf(hj, Wh[base + j], s0);
            s1 = fmaf(hj, Wh[1024 + base + j], s1);
        }
    }
#pragma unroll
    for (int off = 32; off; off >>= 1) {
        s0 += __shfl_down(s0, off);
        s1 += __shfl_down(s1, off);
    }
    if (lane == 0) {
        out[(size_t)row * 2 + 0] = s0 + bh[0];
        out[(size_t)row * 2 + 1] = s1 + bh[1];
    }
}

// ---------------------------------------------------------------------------
extern "C" void kernel_launch(void* const* d_in, const int* in_sizes, int n_in,
                              void* d_out, int out_size, void* d_ws, size_t ws_size,
                              hipStream_t stream)
{
    const float* x  = (const float*)d_in[0];
    const float* sv = (const float*)d_in[1];
    const float* W1 = (const float*)d_in[2];
    const float* b1 = (const float*)d_in[3];
    const float* W2 = (const float*)d_in[4];
    const float* b2 = (const float*)d_in[5];
    const float* Wh = (const float*)d_in[6];
    const float* bh = (const float*)d_in[7];
    float* out = (float*)d_out;
    char* ws = (char*)d_ws;

    // ---- persistent region (~4.6 MB) ----
    constexpr size_t OFF_SV = 0;
    constexpr size_t OFF_W1 = OFF_SV + 524288;
    constexpr size_t OFF_W2 = OFF_W1 + 2097152;
    constexpr size_t OFF_S2 = OFF_W2 + 2097152;
    constexpr size_t PERSIST = OFF_S2 + 4096;

    _Float16* svf = (_Float16*)(ws + OFF_SV);
    _Float16* w1f = (_Float16*)(ws + OFF_W1);
    _Float16* w2f = (_Float16*)(ws + OFF_W2);
    float*    s2v = (float*)(ws + OFF_S2);

    // ---- adaptive batch chunking ----
    int Bc = 65536;
    while (Bc > 256 && PERSIST + (size_t)Bc * 4100ULL > ws_size) Bc >>= 1;

    char* chunk_base = ws + PERSIST;
    _Float16* kb  = (_Float16*)chunk_base;                        // Bc x 1024 fp16
    _Float16* h1b = (_Float16*)(chunk_base + (size_t)Bc * 2048);  // Bc x 1024 fp16
    _Float16* xf  = h1b;                                          // overlapped (dies before h1 written)
    float*    x2v = (float*)(chunk_base + (size_t)Bc * 4096);

    prep_rows_kernel<<<1024 / 4, 256, 0, stream>>>(sv, svf, s2v, 1024);
    cvt_kernel<<<1024, 256, 0, stream>>>(W1, w1f, 262144);
    cvt_kernel<<<1024, 256, 0, stream>>>(W2, w2f, 262144);

    int nchunks = 65536 / Bc;
    int ggrid   = (Bc / 256) * 4;
    for (int c = 0; c < nchunks; ++c) {
        const float* xc = x + (size_t)c * Bc * 256;
        prep_rows_kernel<<<Bc / 4, 256, 0, stream>>>(xc, xf, x2v, Bc);
        gemm256_kernel<0, 256><<<ggrid, 512, 0, stream>>>(xf, svf, kb, x2v, s2v);
        gemm256_kernel<1, 1024><<<ggrid, 512, 0, stream>>>(kb, w1f, h1b, b1, nullptr);
        gemm256_kernel<1, 1024><<<ggrid, 512, 0, stream>>>(h1b, w2f, kb, b2, nullptr);
        head_kernel<<<Bc / 4, 256, 0, stream>>>(kb, Wh, bh, out + (size_t)c * Bc * 2);
    }
}

// Round 11
// 380.924 us; speedup vs baseline: 1.1987x; 1.0163x over previous
//
#include <hip/hip_runtime.h>

typedef _Float16 f16x8 __attribute__((ext_vector_type(8)));
typedef _Float16 f16x4 __attribute__((ext_vector_type(4)));
typedef float    f32x4 __attribute__((ext_vector_type(4)));

#define GAMMA_F 0.00390625f

// ---------------------------------------------------------------------------
// prep: fp32 -> fp16 row conversion + row sum-of-squares (for x and sv)
// ---------------------------------------------------------------------------
__global__ __launch_bounds__(256) void prep_rows_kernel(
    const float* __restrict__ src, _Float16* __restrict__ dst,
    float* __restrict__ sq, int nrows)
{
    int lane = threadIdx.x & 63, w = threadIdx.x >> 6;
    int row = blockIdx.x * 4 + w;
    if (row >= nrows) return;
    float4 v = ((const float4*)(src + (size_t)row * 256))[lane];
    f16x4 h;
    h[0] = (_Float16)v.x; h[1] = (_Float16)v.y;
    h[2] = (_Float16)v.z; h[3] = (_Float16)v.w;
    *((f16x4*)(dst + (size_t)row * 256) + lane) = h;
    float ss = v.x*v.x + v.y*v.y + v.z*v.z + v.w*v.w;
#pragma unroll
    for (int off = 32; off; off >>= 1) ss += __shfl_down(ss, off);
    if (lane == 0) sq[row] = ss;
}

__global__ __launch_bounds__(256) void cvt_kernel(
    const float* __restrict__ src, _Float16* __restrict__ dst, int n4)
{
    int i = blockIdx.x * 256 + threadIdx.x;
    if (i < n4) {
        float4 v = ((const float4*)src)[i];
        f16x4 h;
        h[0] = (_Float16)v.x; h[1] = (_Float16)v.y;
        h[2] = (_Float16)v.z; h[3] = (_Float16)v.w;
        ((f16x4*)dst)[i] = h;
    }
}

// ---------------------------------------------------------------------------
// 256x256-tile 8-phase GEMM, asm-staged, ks-split reads, ONE barrier/phase.
// Phase = [pre-reads + stage] BAR [post-reads + MFMA]. No post-MFMA barrier:
// a wave leaving its MFMA cluster issues the next phase's ds_reads while
// slower waves still MFMA -> cross-wave LDS||MFMA overlap (r10: 46% of
// cycles idle under the 16-barrier lockstep convoy).
// Hazard ledger (re-derived): every stage-overwrite has >=1 barrier after
// the last read of its region; vmcnt gates sit pre-BAR (visibility); gate
// at ph4/ph8 retires exactly the tiles read in the following phases.
//   MODE 0: C = exp(-g*(e0[m] + e1[n] - 2*acc))
//   MODE 1: C = relu(acc + e0[n])
// ---------------------------------------------------------------------------
#define SBAR()   __builtin_amdgcn_s_barrier()
#define RFENCE() asm volatile("" ::: "memory")

#define GLDA(gptr, uoff)                                                       \
    asm volatile("s_mov_b32 m0, %1\n\t"                                        \
                 "global_load_lds_dwordx4 %0, off\n\t"                         \
                 "s_mov_b32 m0, -1"                                            \
                 :: "v"((const void*)(gptr)), "s"(uoff))

#define UOF(x) __builtin_amdgcn_readfirstlane((x) + wb)

// stage half h (rows h*128 .. h*128+127) of the CURRENT A/B tile into slot s
#define STA(s, h) do {                                                         \
    GLDA(aP##h##0, UOF((s)*32768 + (h)*16384));                                \
    GLDA(aP##h##1, UOF((s)*32768 + (h)*16384 + 8192));                         \
} while (0)
#define STB(s, h) do {                                                         \
    GLDA(bP##h##0, UOF(65536 + (s)*32768 + (h)*16384));                        \
    GLDA(bP##h##1, UOF(65536 + (s)*32768 + (h)*16384 + 8192));                 \
} while (0)
#define ADV_A() do { aP00+=64; aP01+=64; aP10+=64; aP11+=64; } while (0)
#define ADV_B() do { bP00+=64; bP01+=64; bP10+=64; bP11+=64; } while (0)

#define PRE_A(s, mh) do { _Pragma("unroll") for (int mi = 0; mi < 4; ++mi)     \
    a0f[mi] = *(const f16x8*)(ldsb + aO0 + (s)*32768 + (mh)*8192 + mi*2048);   \
} while (0)
#define POST_A(s, mh) do { _Pragma("unroll") for (int mi = 0; mi < 4; ++mi)    \
    a1f[mi] = *(const f16x8*)(ldsb + aO1 + (s)*32768 + (mh)*8192 + mi*2048);   \
} while (0)
#define PRE_BA(s, nh) do { _Pragma("unroll") for (int nb = 0; nb < 2; ++nb)    \
    bA0[nb] = *(const f16x8*)(ldsb + bO0 + (s)*32768 + (nh)*4096 + nb*2048);   \
} while (0)
#define POST_BA(s, nh) do { _Pragma("unroll") for (int nb = 0; nb < 2; ++nb)   \
    bA1[nb] = *(const f16x8*)(ldsb + bO1 + (s)*32768 + (nh)*4096 + nb*2048);   \
} while (0)
#define PRE_BB(s, nh) do { _Pragma("unroll") for (int nb = 0; nb < 2; ++nb)    \
    bB0[nb] = *(const f16x8*)(ldsb + bO0 + (s)*32768 + (nh)*4096 + nb*2048);   \
} while (0)
#define POST_BB(s, nh) do { _Pragma("unroll") for (int nb = 0; nb < 2; ++nb)   \
    bB1[nb] = *(const f16x8*)(ldsb + bO1 + (s)*32768 + (nh)*4096 + nb*2048);   \
} while (0)

#define MFMA8(af, bf, mh, nh) do {                                             \
    _Pragma("unroll") for (int mi = 0; mi < 4; ++mi)                           \
    _Pragma("unroll") for (int nb = 0; nb < 2; ++nb)                           \
        acc[(mh)*4+mi][(nh)*2+nb] = __builtin_amdgcn_mfma_f32_16x16x32_f16(    \
            af[mi], bf[nb], acc[(mh)*4+mi][(nh)*2+nb], 0, 0, 0);               \
} while (0)

template <int MODE, int K>
__global__ __launch_bounds__(512, 1) void gemm256_kernel(
    const _Float16* __restrict__ A, const _Float16* __restrict__ B,
    _Float16* __restrict__ C, const float* __restrict__ e0,
    const float* __restrict__ e1)
{
    constexpr int KT = K / 64;
    constexpr int NITER = KT / 2;
    __shared__ f16x8 lds[8192];   // A bytes [0,65536): 2 slots; B: [65536,131072)
    char* ldsb = (char*)lds;

    const int t    = threadIdx.x;
    const int lane = t & 63, w = t >> 6;
    const int wb   = w << 10;                     // wave-uniform LDS base part
    const int wr   = w >> 2, wc = w & 3;          // 2 x 4 wave grid
    const int lrow = lane & 15, kq = lane >> 4;

    // keep lds formally stored-to (reads fed by asm-invisible staging)
    int poison = 0;
    asm volatile("" : "+v"(poison));
    if (poison) lds[0] = f16x8{};

    // XCD-aware bijective swizzle (grid % 8 == 0 by construction)
    int bid  = blockIdx.x;
    int cpx  = (int)(gridDim.x >> 3);
    int lbid = (bid & 7) * cpx + (bid >> 3);
    int bm   = lbid >> 2, bn = lbid & 3;          // NB = 1024/256 = 4
    int rowA0 = bm * 256, rowB0 = bn * 256;

    // LDS-read base byte offsets
    const int aO0 = ((wr*128 + lrow)*8 + ( kq      ^ (lrow & 7))) * 16;
    const int aO1 = ((wr*128 + lrow)*8 + ((4 + kq) ^ (lrow & 7))) * 16;
    const int bO0 = 65536 + ((wc*64 + lrow)*8 + ( kq      ^ (lrow & 7))) * 16;
    const int bO1 = 65536 + ((wc*64 + lrow)*8 + ((4 + kq) ^ (lrow & 7))) * 16;

    // persistent staging pointers: 4 row-blocks x {A,B}, advance +64 elem/tile
    const int prow = t >> 3;
    const int cg   = (t & 7) ^ (prow & 7);
    const _Float16* aP00 = A + (size_t)(rowA0 + prow      ) * K + cg * 8;
    const _Float16* aP01 = aP00 + (size_t) 64 * K;
    const _Float16* aP10 = aP00 + (size_t)128 * K;
    const _Float16* aP11 = aP00 + (size_t)192 * K;
    const _Float16* bP00 = B + (size_t)(rowB0 + prow      ) * K + cg * 8;
    const _Float16* bP01 = bP00 + (size_t) 64 * K;
    const _Float16* bP10 = bP00 + (size_t)128 * K;
    const _Float16* bP11 = bP00 + (size_t)192 * K;

    f32x4 acc[8][4];
#pragma unroll
    for (int i = 0; i < 8; ++i)
#pragma unroll
        for (int j = 0; j < 4; ++j) acc[i][j] = (f32x4){0.f, 0.f, 0.f, 0.f};

    f16x8 a0f[4], a1f[4], bA0[2], bA1[2], bB0[2], bB1[2];

    // ---- prologue: tile0 -> slot0, tile1 -> slot1 ----
    STA(0,0); STA(0,1); STB(0,0); STB(0,1); ADV_A(); ADV_B();
    STA(1,0); STA(1,1); STB(1,0); STB(1,1); ADV_A(); ADV_B();   // now at tile2
    asm volatile("s_waitcnt vmcnt(8)" ::: "memory");            // tile0 landed
    SBAR();

    for (int j = 0; j < NITER; ++j) {
        const bool last = (j == NITER - 1);

        // ---- phase 1: slot0, quad (0,0) ----
        RFENCE();
        PRE_A(0, 0); PRE_BA(0, 0);
        if (j > 0) STA(1, 0);                       // tile 2j+1 A-half0 -> s1
        SBAR();
        POST_A(0, 0); POST_BA(0, 0);
        __builtin_amdgcn_s_setprio(1);
        MFMA8(a0f, bA0, 0, 0); MFMA8(a1f, bA1, 0, 0);
        __builtin_amdgcn_s_setprio(0);
        // ---- phase 2: (0,1) ----
        RFENCE();
        PRE_BB(0, 1);
        if (j > 0) { STA(1, 1); ADV_A(); }          // A now at tile 2j+2
        SBAR();
        POST_BB(0, 1);
        __builtin_amdgcn_s_setprio(1);
        MFMA8(a0f, bB0, 0, 1); MFMA8(a1f, bB1, 0, 1);
        __builtin_amdgcn_s_setprio(0);
        // ---- phase 3: (1,0) ----
        RFENCE();
        PRE_A(0, 1);
        if (!last) STB(0, 0);                       // tile 2j+2 B-half0 -> s0
        SBAR();
        POST_A(0, 1);
        __builtin_amdgcn_s_setprio(1);
        MFMA8(a0f, bA0, 1, 0); MFMA8(a1f, bA1, 1, 0);
        __builtin_amdgcn_s_setprio(0);
        // ---- phase 4: (1,1) + counted vmcnt ----
        RFENCE();
        if (!last) {
            STB(0, 1); ADV_B();                     // B now at tile 2j+3
            asm volatile("s_waitcnt vmcnt(4)" ::: "memory");
        } else {
            asm volatile("s_waitcnt vmcnt(0)" ::: "memory");
        }
        SBAR();
        __builtin_amdgcn_s_setprio(1);
        MFMA8(a0f, bB0, 1, 1); MFMA8(a1f, bB1, 1, 1);
        __builtin_amdgcn_s_setprio(0);
        // ---- phase 5: slot1, quad (0,0) ----
        RFENCE();
        PRE_A(1, 0); PRE_BA(1, 0);
        if (!last) STA(0, 0);                       // tile 2j+2 A-half0 -> s0
        SBAR();
        POST_A(1, 0); POST_BA(1, 0);
        __builtin_amdgcn_s_setprio(1);
        MFMA8(a0f, bA0, 0, 0); MFMA8(a1f, bA1, 0, 0);
        __builtin_amdgcn_s_setprio(0);
        // ---- phase 6: (0,1) ----
        RFENCE();
        PRE_BB(1, 1);
        if (!last) { STA(0, 1); ADV_A(); }          // A now at tile 2j+3
        SBAR();
        POST_BB(1, 1);
        __builtin_amdgcn_s_setprio(1);
        MFMA8(a0f, bB0, 0, 1); MFMA8(a1f, bB1, 0, 1);
        __builtin_amdgcn_s_setprio(0);
        // ---- phase 7: (1,0) ----
        RFENCE();
        PRE_A(1, 1);
        if (!last) STB(1, 0);                       // tile 2j+3 B-half0 -> s1
        SBAR();
        POST_A(1, 1);
        __builtin_amdgcn_s_setprio(1);
        MFMA8(a0f, bA0, 1, 0); MFMA8(a1f, bA1, 1, 0);
        __builtin_amdgcn_s_setprio(0);
        // ---- phase 8: (1,1) + counted vmcnt ----
        RFENCE();
        if (!last) {
            STB(1, 1); ADV_B();                     // B now at tile 2j+4
            asm volatile("s_waitcnt vmcnt(4)" ::: "memory");
        }
        SBAR();
        __builtin_amdgcn_s_setprio(1);
        MFMA8(a0f, bB0, 1, 1); MFMA8(a1f, bB1, 1, 1);
        __builtin_amdgcn_s_setprio(0);
    }

    // ---- epilogue ----
    int gr0 = rowA0 + wr * 128;
    int gc0 = rowB0 + wc * 64;
    float ecol[4];
#pragma unroll
    for (int ni = 0; ni < 4; ++ni)
        ecol[ni] = (MODE == 0) ? e1[gc0 + ni * 16 + lrow]
                               : e0[gc0 + ni * 16 + lrow];
#pragma unroll
    for (int mi = 0; mi < 8; ++mi) {
#pragma unroll
        for (int jj = 0; jj < 4; ++jj) {
            int row = gr0 + mi * 16 + kq * 4 + jj;
            float xr = (MODE == 0) ? e0[row] : 0.f;
            size_t base = (size_t)row * 1024 + gc0 + lrow;
#pragma unroll
            for (int ni = 0; ni < 4; ++ni) {
                float v = acc[mi][ni][jj];
                if (MODE == 0) {
                    v = __expf(-GAMMA_F * (xr + ecol[ni] - 2.f * v));
                } else {
                    v += ecol[ni];
                    v = fmaxf(v, 0.f);
                }
                C[base + (size_t)ni * 16] = (_Float16)v;
            }
        }
    }
}

// ---------------------------------------------------------------------------
// head: out[b][o] = sum_s h2[b][s]*Wh[o][s] + bh[o], o in {0,1}
// ---------------------------------------------------------------------------
__global__ __launch_bounds__(256) void head_kernel(
    const _Float16* __restrict__ h2, const float* __restrict__ Wh,
    const float* __restrict__ bh, float* __restrict__ out)
{
    int lane = threadIdx.x & 63, w = threadIdx.x >> 6;
    int row = blockIdx.x * 4 + w;
    const _Float16* hp = h2 + (size_t)row * 1024;
    float s0 = 0.f, s1 = 0.f;
#pragma unroll
    for (int i = 0; i < 2; ++i) {
        int base = (i * 64 + lane) * 8;
        f16x8 hv = *(const f16x8*)(hp + base);
#pragma unroll
        for (int j = 0; j < 8; ++j) {
            float hj = (float)hv[j];
            s0 = fmaf(hj, Wh[base + j], s0);
            s1 = fmaf(hj, Wh[1024 + base + j], s1);
        }
    }
#pragma unroll
    for (int off = 32; off; off >>= 1) {
        s0 += __shfl_down(s0, off);
        s1 += __shfl_down(s1, off);
    }
    if (lane == 0) {
        out[(size_t)row * 2 + 0] = s0 + bh[0];
        out[(size_t)row * 2 + 1] = s1 + bh[1];
    }
}

// ---------------------------------------------------------------------------
extern "C" void kernel_launch(void* const* d_in, const int* in_sizes, int n_in,
                              void* d_out, int out_size, void* d_ws, size_t ws_size,
                              hipStream_t stream)
{
    const float* x  = (const float*)d_in[0];
    const float* sv = (const float*)d_in[1];
    const float* W1 = (const float*)d_in[2];
    const float* b1 = (const float*)d_in[3];
    const float* W2 = (const float*)d_in[4];
    const float* b2 = (const float*)d_in[5];
    const float* Wh = (const float*)d_in[6];
    const float* bh = (const float*)d_in[7];
    float* out = (float*)d_out;
    char* ws = (char*)d_ws;

    // ---- persistent region (~4.6 MB) ----
    constexpr size_t OFF_SV = 0;
    constexpr size_t OFF_W1 = OFF_SV + 524288;
    constexpr size_t OFF_W2 = OFF_W1 + 2097152;
    constexpr size_t OFF_S2 = OFF_W2 + 2097152;
    constexpr size_t PERSIST = OFF_S2 + 4096;

    _Float16* svf = (_Float16*)(ws + OFF_SV);
    _Float16* w1f = (_Float16*)(ws + OFF_W1);
    _Float16* w2f = (_Float16*)(ws + OFF_W2);
    float*    s2v = (float*)(ws + OFF_S2);

    // ---- adaptive batch chunking ----
    int Bc = 65536;
    while (Bc > 256 && PERSIST + (size_t)Bc * 4100ULL > ws_size) Bc >>= 1;

    char* chunk_base = ws + PERSIST;
    _Float16* kb  = (_Float16*)chunk_base;                        // Bc x 1024 fp16
    _Float16* h1b = (_Float16*)(chunk_base + (size_t)Bc * 2048);  // Bc x 1024 fp16
    _Float16* xf  = h1b;                                          // overlapped (dies before h1 written)
    float*    x2v = (float*)(chunk_base + (size_t)Bc * 4096);

    prep_rows_kernel<<<1024 / 4, 256, 0, stream>>>(sv, svf, s2v, 1024);
    cvt_kernel<<<1024, 256, 0, stream>>>(W1, w1f, 262144);
    cvt_kernel<<<1024, 256, 0, stream>>>(W2, w2f, 262144);

    int nchunks = 65536 / Bc;
    int ggrid   = (Bc / 256) * 4;
    for (int c = 0; c < nchunks; ++c) {
        const float* xc = x + (size_t)c * Bc * 256;
        prep_rows_kernel<<<Bc / 4, 256, 0, stream>>>(xc, xf, x2v, Bc);
        gemm256_kernel<0, 256><<<ggrid, 512, 0, stream>>>(xf, svf, kb, x2v, s2v);
        gemm256_kernel<1, 1024><<<ggrid, 512, 0, stream>>>(kb, w1f, h1b, b1, nullptr);
        gemm256_kernel<1, 1024><<<ggrid, 512, 0, stream>>>(h1b, w2f, kb, b2, nullptr);
        head_kernel<<<Bc / 4, 256, 0, stream>>>(kb, Wh, bh, out + (size_t)c * Bc * 2);
    }
}

// Round 12
// 372.729 us; speedup vs baseline: 1.2250x; 1.0220x over previous
//
#include <hip/hip_runtime.h>

typedef _Float16 f16x8 __attribute__((ext_vector_type(8)));
typedef _Float16 f16x4 __attribute__((ext_vector_type(4)));
typedef float    f32x4 __attribute__((ext_vector_type(4)));

#define GAMMA_F 0.00390625f

// ---------------------------------------------------------------------------
// prep: fp32 -> fp16 row conversion + row sum-of-squares (for x and sv)
// ---------------------------------------------------------------------------
__global__ __launch_bounds__(256) void prep_rows_kernel(
    const float* __restrict__ src, _Float16* __restrict__ dst,
    float* __restrict__ sq, int nrows)
{
    int lane = threadIdx.x & 63, w = threadIdx.x >> 6;
    int row = blockIdx.x * 4 + w;
    if (row >= nrows) return;
    float4 v = ((const float4*)(src + (size_t)row * 256))[lane];
    f16x4 h;
    h[0] = (_Float16)v.x; h[1] = (_Float16)v.y;
    h[2] = (_Float16)v.z; h[3] = (_Float16)v.w;
    *((f16x4*)(dst + (size_t)row * 256) + lane) = h;
    float ss = v.x*v.x + v.y*v.y + v.z*v.z + v.w*v.w;
#pragma unroll
    for (int off = 32; off; off >>= 1) ss += __shfl_down(ss, off);
    if (lane == 0) sq[row] = ss;
}

__global__ __launch_bounds__(256) void cvt_kernel(
    const float* __restrict__ src, _Float16* __restrict__ dst, int n4)
{
    int i = blockIdx.x * 256 + threadIdx.x;
    if (i < n4) {
        float4 v = ((const float4*)src)[i];
        f16x4 h;
        h[0] = (_Float16)v.x; h[1] = (_Float16)v.y;
        h[2] = (_Float16)v.z; h[3] = (_Float16)v.w;
        ((f16x4*)dst)[i] = h;
    }
}

// ---------------------------------------------------------------------------
// 256x256-tile GEMM, asm-staged, FOUR phases/iteration (32 MFMA each).
// r11 measured: wall 1350 cyc/phase = MFMA 515 + LDS ~400 + ~435 fixed
// overhead (barrier+lgkm drain+fence+stage issue) paid 8x/iter. Merging
// quadrant pairs halves the per-iter overhead count: 4 barriers/iter.
// Phase = [RFENCE; ks0 reads (8); stage; (gate)] BAR [ks1 reads (8); 32 MFMA].
// vmcnt ledger (re-derived): stages P1=A-s1,P2=B-s0+vmcnt(4),P3=A-s0,
// P4=B-s1+vmcnt(4); steady state 4 outstanding entering each iter; each
// gate retires exactly the slot read after the following barrier.
//   MODE 0: C = exp(-g*(e0[m] + e1[n] - 2*acc))
//   MODE 1: C = relu(acc + e0[n])
// ---------------------------------------------------------------------------
#define SBAR()   __builtin_amdgcn_s_barrier()
#define RFENCE() asm volatile("" ::: "memory")

#define GLDA(gptr, uoff)                                                       \
    asm volatile("s_mov_b32 m0, %1\n\t"                                        \
                 "global_load_lds_dwordx4 %0, off\n\t"                         \
                 "s_mov_b32 m0, -1"                                            \
                 :: "v"((const void*)(gptr)), "s"(uoff))

#define UOF(x) __builtin_amdgcn_readfirstlane((x) + wb)

// stage half h (rows h*128 .. h*128+127) of the CURRENT A/B tile into slot s
#define STA(s, h) do {                                                         \
    GLDA(aP##h##0, UOF((s)*32768 + (h)*16384));                                \
    GLDA(aP##h##1, UOF((s)*32768 + (h)*16384 + 8192));                         \
} while (0)
#define STB(s, h) do {                                                         \
    GLDA(bP##h##0, UOF(65536 + (s)*32768 + (h)*16384));                        \
    GLDA(bP##h##1, UOF(65536 + (s)*32768 + (h)*16384 + 8192));                 \
} while (0)
#define ADV_A() do { aP00+=64; aP01+=64; aP10+=64; aP11+=64; } while (0)
#define ADV_B() do { bP00+=64; bP01+=64; bP10+=64; bP11+=64; } while (0)

#define RD_A0(s, mh) do { _Pragma("unroll") for (int mi = 0; mi < 4; ++mi)     \
    a0f[mi] = *(const f16x8*)(ldsb + aO0 + (s)*32768 + (mh)*8192 + mi*2048);   \
} while (0)
#define RD_A1(s, mh) do { _Pragma("unroll") for (int mi = 0; mi < 4; ++mi)     \
    a1f[mi] = *(const f16x8*)(ldsb + aO1 + (s)*32768 + (mh)*8192 + mi*2048);   \
} while (0)
#define RD_B0A(s, nh) do { _Pragma("unroll") for (int nb = 0; nb < 2; ++nb)    \
    bA0[nb] = *(const f16x8*)(ldsb + bO0 + (s)*32768 + (nh)*4096 + nb*2048);   \
} while (0)
#define RD_B1A(s, nh) do { _Pragma("unroll") for (int nb = 0; nb < 2; ++nb)    \
    bA1[nb] = *(const f16x8*)(ldsb + bO1 + (s)*32768 + (nh)*4096 + nb*2048);   \
} while (0)
#define RD_B0B(s, nh) do { _Pragma("unroll") for (int nb = 0; nb < 2; ++nb)    \
    bB0[nb] = *(const f16x8*)(ldsb + bO0 + (s)*32768 + (nh)*4096 + nb*2048);   \
} while (0)
#define RD_B1B(s, nh) do { _Pragma("unroll") for (int nb = 0; nb < 2; ++nb)    \
    bB1[nb] = *(const f16x8*)(ldsb + bO1 + (s)*32768 + (nh)*4096 + nb*2048);   \
} while (0)

#define MFMA8(af, bf, mh, nh) do {                                             \
    _Pragma("unroll") for (int mi = 0; mi < 4; ++mi)                           \
    _Pragma("unroll") for (int nb = 0; nb < 2; ++nb)                           \
        acc[(mh)*4+mi][(nh)*2+nb] = __builtin_amdgcn_mfma_f32_16x16x32_f16(    \
            af[mi], bf[nb], acc[(mh)*4+mi][(nh)*2+nb], 0, 0, 0);               \
} while (0)

// 32 MFMA for row-half mh: quads (mh,0) then (mh,1), ks0 then ks1 inside
#define MFMA32(mh) do {                                                        \
    __builtin_amdgcn_s_setprio(1);                                             \
    MFMA8(a0f, bA0, mh, 0); MFMA8(a1f, bA1, mh, 0);                            \
    MFMA8(a0f, bB0, mh, 1); MFMA8(a1f, bB1, mh, 1);                            \
    __builtin_amdgcn_s_setprio(0);                                             \
} while (0)

template <int MODE, int K>
__global__ __launch_bounds__(512, 1) void gemm256_kernel(
    const _Float16* __restrict__ A, const _Float16* __restrict__ B,
    _Float16* __restrict__ C, const float* __restrict__ e0,
    const float* __restrict__ e1)
{
    constexpr int KT = K / 64;
    constexpr int NITER = KT / 2;
    __shared__ f16x8 lds[8192];   // A bytes [0,65536): 2 slots; B: [65536,131072)
    char* ldsb = (char*)lds;

    const int t    = threadIdx.x;
    const int lane = t & 63, w = t >> 6;
    const int wb   = w << 10;                     // wave-uniform LDS base part
    const int wr   = w >> 2, wc = w & 3;          // 2 x 4 wave grid
    const int lrow = lane & 15, kq = lane >> 4;

    // keep lds formally stored-to (reads fed by asm-invisible staging)
    int poison = 0;
    asm volatile("" : "+v"(poison));
    if (poison) lds[0] = f16x8{};

    // XCD-aware bijective swizzle (grid % 8 == 0 by construction)
    int bid  = blockIdx.x;
    int cpx  = (int)(gridDim.x >> 3);
    int lbid = (bid & 7) * cpx + (bid >> 3);
    int bm   = lbid >> 2, bn = lbid & 3;          // NB = 1024/256 = 4
    int rowA0 = bm * 256, rowB0 = bn * 256;

    // LDS-read base byte offsets
    const int aO0 = ((wr*128 + lrow)*8 + ( kq      ^ (lrow & 7))) * 16;
    const int aO1 = ((wr*128 + lrow)*8 + ((4 + kq) ^ (lrow & 7))) * 16;
    const int bO0 = 65536 + ((wc*64 + lrow)*8 + ( kq      ^ (lrow & 7))) * 16;
    const int bO1 = 65536 + ((wc*64 + lrow)*8 + ((4 + kq) ^ (lrow & 7))) * 16;

    // persistent staging pointers: 4 row-blocks x {A,B}, advance +64 elem/tile
    const int prow = t >> 3;
    const int cg   = (t & 7) ^ (prow & 7);
    const _Float16* aP00 = A + (size_t)(rowA0 + prow      ) * K + cg * 8;
    const _Float16* aP01 = aP00 + (size_t) 64 * K;
    const _Float16* aP10 = aP00 + (size_t)128 * K;
    const _Float16* aP11 = aP00 + (size_t)192 * K;
    const _Float16* bP00 = B + (size_t)(rowB0 + prow      ) * K + cg * 8;
    const _Float16* bP01 = bP00 + (size_t) 64 * K;
    const _Float16* bP10 = bP00 + (size_t)128 * K;
    const _Float16* bP11 = bP00 + (size_t)192 * K;

    f32x4 acc[8][4];
#pragma unroll
    for (int i = 0; i < 8; ++i)
#pragma unroll
        for (int j = 0; j < 4; ++j) acc[i][j] = (f32x4){0.f, 0.f, 0.f, 0.f};

    f16x8 a0f[4], a1f[4], bA0[2], bA1[2], bB0[2], bB1[2];

    // ---- prologue: tile0 -> slot0, tile1 -> slot1 ----
    STA(0,0); STA(0,1); STB(0,0); STB(0,1); ADV_A(); ADV_B();
    STA(1,0); STA(1,1); STB(1,0); STB(1,1); ADV_A(); ADV_B();   // now at tile2
    asm volatile("s_waitcnt vmcnt(8)" ::: "memory");            // tile0 landed
    SBAR();

    for (int j = 0; j < NITER; ++j) {
        const bool last = (j == NITER - 1);

        // ---- P1: slot0, row-half 0 (quads (0,0)+(0,1)) ----
        RFENCE();
        RD_A0(0, 0); RD_B0A(0, 0); RD_B0B(0, 1);
        if (j > 0) { STA(1, 0); STA(1, 1); ADV_A(); }   // tile 2j+1 A -> s1
        SBAR();
        RD_A1(0, 0); RD_B1A(0, 0); RD_B1B(0, 1);
        MFMA32(0);
        // ---- P2: slot0, row-half 1 ----
        RFENCE();
        RD_A0(0, 1);
        if (!last) {
            STB(0, 0); STB(0, 1); ADV_B();              // tile 2j+2 B -> s0
            asm volatile("s_waitcnt vmcnt(4)" ::: "memory");  // slot1 landed
        } else {
            asm volatile("s_waitcnt vmcnt(0)" ::: "memory");
        }
        SBAR();
        RD_A1(0, 1);
        MFMA32(1);
        // ---- P3: slot1, row-half 0 ----
        RFENCE();
        RD_A0(1, 0); RD_B0A(1, 0); RD_B0B(1, 1);
        if (!last) { STA(0, 0); STA(0, 1); ADV_A(); }   // tile 2j+2 A -> s0
        SBAR();
        RD_A1(1, 0); RD_B1A(1, 0); RD_B1B(1, 1);
        MFMA32(0);
        // ---- P4: slot1, row-half 1 ----
        RFENCE();
        RD_A0(1, 1);
        if (!last) {
            STB(1, 0); STB(1, 1); ADV_B();              // tile 2j+3 B -> s1
            asm volatile("s_waitcnt vmcnt(4)" ::: "memory");  // slot0 landed
        }
        SBAR();
        RD_A1(1, 1);
        MFMA32(1);
    }

    // ---- epilogue ----
    int gr0 = rowA0 + wr * 128;
    int gc0 = rowB0 + wc * 64;
    float ecol[4];
#pragma unroll
    for (int ni = 0; ni < 4; ++ni)
        ecol[ni] = (MODE == 0) ? e1[gc0 + ni * 16 + lrow]
                               : e0[gc0 + ni * 16 + lrow];
#pragma unroll
    for (int mi = 0; mi < 8; ++mi) {
#pragma unroll
        for (int jj = 0; jj < 4; ++jj) {
            int row = gr0 + mi * 16 + kq * 4 + jj;
            float xr = (MODE == 0) ? e0[row] : 0.f;
            size_t base = (size_t)row * 1024 + gc0 + lrow;
#pragma unroll
            for (int ni = 0; ni < 4; ++ni) {
                float v = acc[mi][ni][jj];
                if (MODE == 0) {
                    v = __expf(-GAMMA_F * (xr + ecol[ni] - 2.f * v));
                } else {
                    v += ecol[ni];
                    v = fmaxf(v, 0.f);
                }
                C[base + (size_t)ni * 16] = (_Float16)v;
            }
        }
    }
}

// ---------------------------------------------------------------------------
// head: out[b][o] = sum_s h2[b][s]*Wh[o][s] + bh[o], o in {0,1}
// ---------------------------------------------------------------------------
__global__ __launch_bounds__(256) void head_kernel(
    const _Float16* __restrict__ h2, const float* __restrict__ Wh,
    const float* __restrict__ bh, float* __restrict__ out)
{
    int lane = threadIdx.x & 63, w = threadIdx.x >> 6;
    int row = blockIdx.x * 4 + w;
    const _Float16* hp = h2 + (size_t)row * 1024;
    float s0 = 0.f, s1 = 0.f;
#pragma unroll
    for (int i = 0; i < 2; ++i) {
        int base = (i * 64 + lane) * 8;
        f16x8 hv = *(const f16x8*)(hp + base);
#pragma unroll
        for (int j = 0; j < 8; ++j) {
            float hj = (float)hv[j];
            s0 = fmaf(hj, Wh[base + j], s0);
            s1 = fmaf(hj, Wh[1024 + base + j], s1);
        }
    }
#pragma unroll
    for (int off = 32; off; off >>= 1) {
        s0 += __shfl_down(s0, off);
        s1 += __shfl_down(s1, off);
    }
    if (lane == 0) {
        out[(size_t)row * 2 + 0] = s0 + bh[0];
        out[(size_t)row * 2 + 1] = s1 + bh[1];
    }
}

// ---------------------------------------------------------------------------
extern "C" void kernel_launch(void* const* d_in, const int* in_sizes, int n_in,
                              void* d_out, int out_size, void* d_ws, size_t ws_size,
                              hipStream_t stream)
{
    const float* x  = (const float*)d_in[0];
    const float* sv = (const float*)d_in[1];
    const float* W1 = (const float*)d_in[2];
    const float* b1 = (const float*)d_in[3];
    const float* W2 = (const float*)d_in[4];
    const float* b2 = (const float*)d_in[5];
    const float* Wh = (const float*)d_in[6];
    const float* bh = (const float*)d_in[7];
    float* out = (float*)d_out;
    char* ws = (char*)d_ws;

    // ---- persistent region (~4.6 MB) ----
    constexpr size_t OFF_SV = 0;
    constexpr size_t OFF_W1 = OFF_SV + 524288;
    constexpr size_t OFF_W2 = OFF_W1 + 2097152;
    constexpr size_t OFF_S2 = OFF_W2 + 2097152;
    constexpr size_t PERSIST = OFF_S2 + 4096;

    _Float16* svf = (_Float16*)(ws + OFF_SV);
    _Float16* w1f = (_Float16*)(ws + OFF_W1);
    _Float16* w2f = (_Float16*)(ws + OFF_W2);
    float*    s2v = (float*)(ws + OFF_S2);

    // ---- adaptive batch chunking ----
    int Bc = 65536;
    while (Bc > 256 && PERSIST + (size_t)Bc * 4100ULL > ws_size) Bc >>= 1;

    char* chunk_base = ws + PERSIST;
    _Float16* kb  = (_Float16*)chunk_base;                        // Bc x 1024 fp16
    _Float16* h1b = (_Float16*)(chunk_base + (size_t)Bc * 2048);  // Bc x 1024 fp16
    _Float16* xf  = h1b;                                          // overlapped (dies before h1 written)
    float*    x2v = (float*)(chunk_base + (size_t)Bc * 4096);

    prep_rows_kernel<<<1024 / 4, 256, 0, stream>>>(sv, svf, s2v, 1024);
    cvt_kernel<<<1024, 256, 0, stream>>>(W1, w1f, 262144);
    cvt_kernel<<<1024, 256, 0, stream>>>(W2, w2f, 262144);

    int nchunks = 65536 / Bc;
    int ggrid   = (Bc / 256) * 4;
    for (int c = 0; c < nchunks; ++c) {
        const float* xc = x + (size_t)c * Bc * 256;
        prep_rows_kernel<<<Bc / 4, 256, 0, stream>>>(xc, xf, x2v, Bc);
        gemm256_kernel<0, 256><<<ggrid, 512, 0, stream>>>(xf, svf, kb, x2v, s2v);
        gemm256_kernel<1, 1024><<<ggrid, 512, 0, stream>>>(kb, w1f, h1b, b1, nullptr);
        gemm256_kernel<1, 1024><<<ggrid, 512, 0, stream>>>(h1b, w2f, kb, b2, nullptr);
        head_kernel<<<Bc / 4, 256, 0, stream>>>(kb, Wh, bh, out + (size_t)c * Bc * 2);
    }
}